// Round 1
// baseline (261.668 us; speedup 1.0000x reference)
//
#include <hip/hip_runtime.h>
#include <hip/hip_bf16.h>
#include <stdint.h>

#define M_BATCH 1024
#define N_OUT   4096
#define K_IN    4096

#define BM 128
#define BN 128
#define BK 64
#define KPER  (K_IN / 2)        // 2048 per intra-block k-half
#define KITER (KPER / BK)       // 32

typedef __attribute__((ext_vector_type(8))) __bf16 bf16x8_t;
typedef __attribute__((ext_vector_type(4))) float f32x4_t;
typedef __attribute__((ext_vector_type(4))) float fvec4;

__device__ __forceinline__ unsigned short f2bf_bits(float f) {
    union { __hip_bfloat16 h; unsigned short u; } cvt;
    cvt.h = __float2bfloat16(f);  // RNE
    return cvt.u;
}

struct __align__(8) US4 { unsigned short x, y, z, w; };

// Kernel 1: w_bf16 = bf16(mu + eps*sigma); x_bf16 = bf16(x).
// 1M threads, exact trip counts, all loads hoisted for ILP (13 in flight).
// R6 change: PLAIN (cached) loads on the fp32 streams. They are re-read every
// bench iteration and 218 MB of them nearly fits the 256 MB Infinity Cache;
// the previous nontemporal hint told L2/MALL not to retain them, which is why
// FETCH_SIZE showed ~109 MB of HBM misses per iteration on data that should
// be LLC-resident. Expect FETCH_SIZE to drop and prep to move toward its
// ~41 us traffic floor (260 MB @ 6.3 TB/s).
__global__ __launch_bounds__(256) void prep_kernel(
    const float* __restrict__ x,
    const float* __restrict__ wmu,
    const float* __restrict__ wsig,
    const float* __restrict__ epsw,
    unsigned short* __restrict__ wb,
    unsigned short* __restrict__ xb)
{
    const size_t tid = (size_t)blockIdx.x * blockDim.x + threadIdx.x;
    const size_t T   = (size_t)1048576;          // 4096 blocks x 256 threads

    const fvec4* wmu4  = (const fvec4*)wmu;
    const fvec4* wsig4 = (const fvec4*)wsig;
    const fvec4* epsw4 = (const fvec4*)epsw;
    US4* wb4 = (US4*)wb;

    fvec4 m[4], s[4], e[4];
    #pragma unroll
    for (int r = 0; r < 4; ++r) {
        const size_t i = tid + (size_t)r * T;    // NW4 = 4T exactly
        m[r] = wmu4[i];
        s[r] = wsig4[i];
        e[r] = epsw4[i];
    }
    #pragma unroll
    for (int r = 0; r < 4; ++r) {
        US4 o;
        o.x = f2bf_bits(fmaf(e[r].x, s[r].x, m[r].x));
        o.y = f2bf_bits(fmaf(e[r].y, s[r].y, m[r].y));
        o.z = f2bf_bits(fmaf(e[r].z, s[r].z, m[r].z));
        o.w = f2bf_bits(fmaf(e[r].w, s[r].w, m[r].w));
        wb4[tid + (size_t)r * T] = o;
    }

    // x: NX4 = T exactly, one fvec4 per thread.
    fvec4 v = ((const fvec4*)x)[tid];
    US4 o;
    o.x = f2bf_bits(v.x);
    o.y = f2bf_bits(v.y);
    o.z = f2bf_bits(v.z);
    o.w = f2bf_bits(v.w);
    ((US4*)xb)[tid] = o;
}

// Kernel 2: C = A @ B^T + bias, written once (no atomics, no pre-zero).
// A=[M][K] bf16, B=[N][K] bf16. 128x128 tile, grid 256 linear = 1 block/CU.
// XCD-aware decode: bn = (b&7) + 8*((b>>3)&3), bm = b>>5. Under round-robin
// block->XCD dispatch (XCD = b%8), the 8 blocks sharing a B-panel land on ONE
// XCD, whose 4 MB L2 holds exactly its 4 bf16 B-panels -> B-panel re-reads
// become L2 hits instead of LLC traffic. Performance-only heuristic.
// 512 threads = 8 waves: waves 0-3 compute k in [0,2048), waves 4-7
// k in [2048,4096), same four 64x64 quadrants (acc[4][4]); partials reduced
// through LDS in the epilogue. LDS: 2 x 64 KB double buffer; XOR chunk
// swizzle on the GLOBAL source address (de-swizzled at ds_read) keeps both
// fill and frag reads conflict-free. Single barrier per K-iter with
// prefetch-after-barrier so the global->LDS DMA overlaps MFMA.
__global__ __launch_bounds__(512, 2) void gemm_bt_kernel(
    const unsigned short* __restrict__ A,
    const unsigned short* __restrict__ B,
    const float* __restrict__ bmu,
    const float* __restrict__ bsig,
    const float* __restrict__ ebias,
    float* __restrict__ C)
{
    // Layout (per buffer, 4096 x 16B chunks = 64 KB):
    //   chunks [0,2048): A  = [half][128 rows][8 chunks]
    //   chunks [2048,4096): B, same shape.
    __shared__ unsigned short lds[2 * 32768];

    const int t   = threadIdx.x;
    const int b   = blockIdx.x;
    const int bn  = (b & 7) | (((b >> 3) & 3) << 3);   // 0..31, same-bn => same XCD
    const int bm  = b >> 5;                             // 0..7
    const int bm0 = bm * BM;
    const int bn0 = bn * BN;
    const int lane  = t & 63;
    const int wave  = t >> 6;
    const int khalf = wave >> 2;          // 0 or 1: which k-half this wave computes
    const int quadw = wave & 3;
    const int wrow  = (quadw >> 1) * 64;
    const int wcol  = (quadw & 1) * 64;
    const int lm    = lane & 15;
    const int quad  = lane >> 4;

    f32x4_t acc[4][4] = {};

    // Staging: thread t, step s stages global chunk g = t + 512*s into
    // LDS byte offset g*16. Decode: s<4 -> A, s>=4 -> B; half=(s>>1)&1;
    // row=(t>>3)+(s&1)*64; phys chunk j=t&7 -> fetch logical j^(row&7).
    const unsigned short* srcs[8];
    const int rlow = t >> 3;                      // 0..63
    const int jsw  = ((t & 7) ^ (rlow & 7)) * 8;  // swizzled source k-offset (elems)
    #pragma unroll
    for (int s = 0; s < 8; ++s) {
        const int row  = rlow + (s & 1) * 64;
        const int half = (s >> 1) & 1;
        const unsigned short* base = (s < 4)
            ? (A + (size_t)(bm0 + row) * K_IN)
            : (B + (size_t)(bn0 + row) * K_IN);
        srcs[s] = base + half * KPER + jsw;
    }
    char* dst0 = (char*)lds + t * 16;

    // Stage tile 0 into buffer 0.
    #pragma unroll
    for (int s = 0; s < 8; ++s)
        __builtin_amdgcn_global_load_lds(
            (const __attribute__((address_space(1))) void*)(srcs[s]),
            (__attribute__((address_space(3))) void*)(dst0 + s * 8192), 16, 0, 0);

    for (int it = 0; it < KITER; ++it) {
        __syncthreads();  // buf(it&1) ready; prior reads of other buf done

        if (it + 1 < KITER) {
            const int koff = (it + 1) * BK;
            const int nb   = ((it + 1) & 1) * 65536;
            #pragma unroll
            for (int s = 0; s < 8; ++s)
                __builtin_amdgcn_global_load_lds(
                    (const __attribute__((address_space(1))) void*)(srcs[s] + koff),
                    (__attribute__((address_space(3))) void*)(dst0 + nb + s * 8192), 16, 0, 0);
        }

        const unsigned short* Lb = lds + (it & 1) * 32768;
        const unsigned short* Ah = Lb + khalf * 8192;           // A, this wave's half
        const unsigned short* Bh = Lb + 16384 + khalf * 8192;   // B, this wave's half

        #pragma unroll
        for (int kk = 0; kk < 2; ++kk) {          // two 16x16x32 K-steps per BK=64
            const int p = ((kk * 4) + quad) ^ (lm & 7);  // de-swizzled chunk
            bf16x8_t a_frag[4], b_frag[4];
            #pragma unroll
            for (int im = 0; im < 4; im++)
                a_frag[im] = *(const bf16x8_t*)(Ah + ((wrow + im * 16 + lm) * 8 + p) * 8);
            #pragma unroll
            for (int jn = 0; jn < 4; jn++)
                b_frag[jn] = *(const bf16x8_t*)(Bh + ((wcol + jn * 16 + lm) * 8 + p) * 8);
            #pragma unroll
            for (int im = 0; im < 4; im++)
                #pragma unroll
                for (int jn = 0; jn < 4; jn++)
                    acc[im][jn] = __builtin_amdgcn_mfma_f32_16x16x32_bf16(
                        a_frag[im], b_frag[jn], acc[im][jn], 0, 0, 0);
        }
    }

    // Epilogue: reduce the two k-halves through LDS, add bias, store once.
    // Last compute used buffer 1 (bytes [64K,128K)); the 64 KB reduction
    // region reuses buffer 0 — disjoint, so no barrier needed before writes.
    f32x4_t* red = (f32x4_t*)lds;   // 4 regions x 1024 f32x4 (16 KB each)
    if (wave >= 4) {
        #pragma unroll
        for (int im = 0; im < 4; im++)
            #pragma unroll
            for (int jn = 0; jn < 4; jn++)
                red[quadw * 1024 + (im * 4 + jn) * 64 + lane] = acc[im][jn];
    }
    __syncthreads();
    if (wave < 4) {
        #pragma unroll
        for (int jn = 0; jn < 4; jn++) {
            const int gn = bn0 + wcol + jn * 16 + lm;
            const float bias = bmu[gn] + ebias[gn] * bsig[gn];
            #pragma unroll
            for (int im = 0; im < 4; im++) {
                const f32x4_t part = red[quadw * 1024 + (im * 4 + jn) * 64 + lane];
                const int gm0 = bm0 + wrow + im * 16 + quad * 4;
                #pragma unroll
                for (int r = 0; r < 4; r++)
                    C[(size_t)(gm0 + r) * N_OUT + gn] = acc[im][jn][r] + part[r] + bias;
            }
        }
    }
}

// Insurance path if d_ws is too small for the bf16 staging buffers.
__global__ __launch_bounds__(256) void naive_kernel(
    const float* __restrict__ x, const float* __restrict__ wmu,
    const float* __restrict__ wsig, const float* __restrict__ bmu,
    const float* __restrict__ bsig, const float* __restrict__ epsw,
    const float* __restrict__ epsb, float* __restrict__ out)
{
    const int o = blockIdx.x * blockDim.x + threadIdx.x;
    const int b = blockIdx.y;
    const float4* xr = (const float4*)(x + (size_t)b * K_IN);
    const float4* mr = (const float4*)(wmu + (size_t)o * K_IN);
    const float4* sr = (const float4*)(wsig + (size_t)o * K_IN);
    const float4* er = (const float4*)(epsw + (size_t)o * K_IN);
    float s = 0.f;
    for (int k = 0; k < K_IN / 4; k++) {
        float4 xv = xr[k], m = mr[k], sg = sr[k], e = er[k];
        s += xv.x * fmaf(e.x, sg.x, m.x);
        s += xv.y * fmaf(e.y, sg.y, m.y);
        s += xv.z * fmaf(e.z, sg.z, m.z);
        s += xv.w * fmaf(e.w, sg.w, m.w);
    }
    out[(size_t)b * N_OUT + o] = s + bmu[o] + epsb[o] * bsig[o];
}

extern "C" void kernel_launch(void* const* d_in, const int* in_sizes, int n_in,
                              void* d_out, int out_size, void* d_ws, size_t ws_size,
                              hipStream_t stream)
{
    const float* x    = (const float*)d_in[0];
    const float* wmu  = (const float*)d_in[1];
    const float* wsig = (const float*)d_in[2];
    const float* bmu  = (const float*)d_in[3];
    const float* bsig = (const float*)d_in[4];
    const float* epsw = (const float*)d_in[5];
    const float* epsb = (const float*)d_in[6];
    float* out = (float*)d_out;

    const size_t need = ((size_t)N_OUT * K_IN + (size_t)M_BATCH * K_IN) * sizeof(unsigned short);
    if (ws_size >= need) {
        unsigned short* wb = (unsigned short*)d_ws;                  // [N][K] bf16
        unsigned short* xb = wb + (size_t)N_OUT * K_IN;              // [M][K] bf16
        prep_kernel<<<4096, 256, 0, stream>>>(x, wmu, wsig, epsw, wb, xb);
        gemm_bt_kernel<<<256, 512, 0, stream>>>(xb, wb, bmu, bsig, epsb, out);
    } else {
        dim3 grid(N_OUT / 256, M_BATCH);
        naive_kernel<<<grid, 256, 0, stream>>>(x, wmu, wsig, bmu, bsig, epsw, epsb, out);
    }
}

// Round 3
// 254.335 us; speedup vs baseline: 1.0288x; 1.0288x over previous
//
#include <hip/hip_runtime.h>
#include <hip/hip_bf16.h>
#include <stdint.h>

#define M_BATCH 1024
#define N_OUT   4096
#define K_IN    4096

#define BM 128
#define BN 128
#define BK 64
#define KPER  (K_IN / 2)        // 2048 per intra-block k-half
#define KITER (KPER / BK)       // 32

typedef __attribute__((ext_vector_type(8))) __bf16 bf16x8_t;
typedef __attribute__((ext_vector_type(4))) float f32x4_t;
typedef __attribute__((ext_vector_type(4))) float fvec4;
typedef __attribute__((ext_vector_type(4))) unsigned short us4_t;  // vector: OK for nontemporal builtins

__device__ __forceinline__ unsigned short f2bf_bits(float f) {
    union { __hip_bfloat16 h; unsigned short u; } cvt;
    cvt.h = __float2bfloat16(f);  // RNE
    return cvt.u;
}

// Kernel 1: w_bf16 = bf16(mu + eps*sigma); x_bf16 = bf16(x).
// 1M threads, exact trip counts, all loads hoisted for ILP (13 in flight).
// R0 evidence: NT loads on the fp32 streams are REQUIRED — removing them kept
// FETCH_SIZE constant (106.5 MB; the MALL retains ~half of the 218 MB stream
// regardless of the hint) but dropped effective BW 4.9 -> 3.0 TB/s by
// thrashing the 4 MB/XCD L2s with a stream that can't fit. NT = skip L2,
// let MALL do the caching.
// R2 change: NT *stores* for wb/xb too (as us4_t vectors — struct US4 was
// rejected by the builtin). Consumers (gemm blocks) sit on other XCDs, so
// producer-side L2 write-allocate is pure pollution in the same L2 the load
// stream transits.
__global__ __launch_bounds__(256) void prep_kernel(
    const float* __restrict__ x,
    const float* __restrict__ wmu,
    const float* __restrict__ wsig,
    const float* __restrict__ epsw,
    unsigned short* __restrict__ wb,
    unsigned short* __restrict__ xb)
{
    const size_t tid = (size_t)blockIdx.x * blockDim.x + threadIdx.x;
    const size_t T   = (size_t)1048576;          // 4096 blocks x 256 threads

    const fvec4* wmu4  = (const fvec4*)wmu;
    const fvec4* wsig4 = (const fvec4*)wsig;
    const fvec4* epsw4 = (const fvec4*)epsw;
    us4_t* wb4 = (us4_t*)wb;

    fvec4 m[4], s[4], e[4];
    #pragma unroll
    for (int r = 0; r < 4; ++r) {
        const size_t i = tid + (size_t)r * T;    // NW4 = 4T exactly
        m[r] = __builtin_nontemporal_load(wmu4  + i);
        s[r] = __builtin_nontemporal_load(wsig4 + i);
        e[r] = __builtin_nontemporal_load(epsw4 + i);
    }
    #pragma unroll
    for (int r = 0; r < 4; ++r) {
        us4_t o;
        o.x = f2bf_bits(fmaf(e[r].x, s[r].x, m[r].x));
        o.y = f2bf_bits(fmaf(e[r].y, s[r].y, m[r].y));
        o.z = f2bf_bits(fmaf(e[r].z, s[r].z, m[r].z));
        o.w = f2bf_bits(fmaf(e[r].w, s[r].w, m[r].w));
        __builtin_nontemporal_store(o, wb4 + (tid + (size_t)r * T));
    }

    // x: NX4 = T exactly, one fvec4 per thread.
    fvec4 v = __builtin_nontemporal_load((const fvec4*)x + tid);
    us4_t o;
    o.x = f2bf_bits(v.x);
    o.y = f2bf_bits(v.y);
    o.z = f2bf_bits(v.z);
    o.w = f2bf_bits(v.w);
    __builtin_nontemporal_store(o, (us4_t*)xb + tid);
}

// Kernel 2: C = A @ B^T + bias, written once (no atomics, no pre-zero).
// A=[M][K] bf16, B=[N][K] bf16. 128x128 tile, grid 256 linear = 1 block/CU.
// XCD-aware decode: bn = (b&7) + 8*((b>>3)&3), bm = b>>5. Under round-robin
// block->XCD dispatch (XCD = b%8), the 8 blocks sharing a B-panel land on ONE
// XCD, whose 4 MB L2 holds exactly its 4 bf16 B-panels -> B-panel re-reads
// become L2 hits instead of LLC traffic. Performance-only heuristic.
// 512 threads = 8 waves: waves 0-3 compute k in [0,2048), waves 4-7
// k in [2048,4096), same four 64x64 quadrants (acc[4][4]); partials reduced
// through LDS in the epilogue. LDS: 2 x 64 KB double buffer; XOR chunk
// swizzle on the GLOBAL source address (de-swizzled at ds_read) keeps both
// fill and frag reads conflict-free. Single barrier per K-iter with
// prefetch-after-barrier so the global->LDS DMA overlaps MFMA.
__global__ __launch_bounds__(512, 2) void gemm_bt_kernel(
    const unsigned short* __restrict__ A,
    const unsigned short* __restrict__ B,
    const float* __restrict__ bmu,
    const float* __restrict__ bsig,
    const float* __restrict__ ebias,
    float* __restrict__ C)
{
    // Layout (per buffer, 4096 x 16B chunks = 64 KB):
    //   chunks [0,2048): A  = [half][128 rows][8 chunks]
    //   chunks [2048,4096): B, same shape.
    __shared__ unsigned short lds[2 * 32768];

    const int t   = threadIdx.x;
    const int b   = blockIdx.x;
    const int bn  = (b & 7) | (((b >> 3) & 3) << 3);   // 0..31, same-bn => same XCD
    const int bm  = b >> 5;                             // 0..7
    const int bm0 = bm * BM;
    const int bn0 = bn * BN;
    const int lane  = t & 63;
    const int wave  = t >> 6;
    const int khalf = wave >> 2;          // 0 or 1: which k-half this wave computes
    const int quadw = wave & 3;
    const int wrow  = (quadw >> 1) * 64;
    const int wcol  = (quadw & 1) * 64;
    const int lm    = lane & 15;
    const int quad  = lane >> 4;

    f32x4_t acc[4][4] = {};

    // Staging: thread t, step s stages global chunk g = t + 512*s into
    // LDS byte offset g*16. Decode: s<4 -> A, s>=4 -> B; half=(s>>1)&1;
    // row=(t>>3)+(s&1)*64; phys chunk j=t&7 -> fetch logical j^(row&7).
    const unsigned short* srcs[8];
    const int rlow = t >> 3;                      // 0..63
    const int jsw  = ((t & 7) ^ (rlow & 7)) * 8;  // swizzled source k-offset (elems)
    #pragma unroll
    for (int s = 0; s < 8; ++s) {
        const int row  = rlow + (s & 1) * 64;
        const int half = (s >> 1) & 1;
        const unsigned short* base = (s < 4)
            ? (A + (size_t)(bm0 + row) * K_IN)
            : (B + (size_t)(bn0 + row) * K_IN);
        srcs[s] = base + half * KPER + jsw;
    }
    char* dst0 = (char*)lds + t * 16;

    // Stage tile 0 into buffer 0.
    #pragma unroll
    for (int s = 0; s < 8; ++s)
        __builtin_amdgcn_global_load_lds(
            (const __attribute__((address_space(1))) void*)(srcs[s]),
            (__attribute__((address_space(3))) void*)(dst0 + s * 8192), 16, 0, 0);

    for (int it = 0; it < KITER; ++it) {
        __syncthreads();  // buf(it&1) ready; prior reads of other buf done

        if (it + 1 < KITER) {
            const int koff = (it + 1) * BK;
            const int nb   = ((it + 1) & 1) * 65536;
            #pragma unroll
            for (int s = 0; s < 8; ++s)
                __builtin_amdgcn_global_load_lds(
                    (const __attribute__((address_space(1))) void*)(srcs[s] + koff),
                    (__attribute__((address_space(3))) void*)(dst0 + nb + s * 8192), 16, 0, 0);
        }

        const unsigned short* Lb = lds + (it & 1) * 32768;
        const unsigned short* Ah = Lb + khalf * 8192;           // A, this wave's half
        const unsigned short* Bh = Lb + 16384 + khalf * 8192;   // B, this wave's half

        #pragma unroll
        for (int kk = 0; kk < 2; ++kk) {          // two 16x16x32 K-steps per BK=64
            const int p = ((kk * 4) + quad) ^ (lm & 7);  // de-swizzled chunk
            bf16x8_t a_frag[4], b_frag[4];
            #pragma unroll
            for (int im = 0; im < 4; im++)
                a_frag[im] = *(const bf16x8_t*)(Ah + ((wrow + im * 16 + lm) * 8 + p) * 8);
            #pragma unroll
            for (int jn = 0; jn < 4; jn++)
                b_frag[jn] = *(const bf16x8_t*)(Bh + ((wcol + jn * 16 + lm) * 8 + p) * 8);
            #pragma unroll
            for (int im = 0; im < 4; im++)
                #pragma unroll
                for (int jn = 0; jn < 4; jn++)
                    acc[im][jn] = __builtin_amdgcn_mfma_f32_16x16x32_bf16(
                        a_frag[im], b_frag[jn], acc[im][jn], 0, 0, 0);
        }
    }

    // Epilogue: reduce the two k-halves through LDS, add bias, store once.
    // Last compute used buffer 1 (bytes [64K,128K)); the 64 KB reduction
    // region reuses buffer 0 — disjoint, so no barrier needed before writes.
    f32x4_t* red = (f32x4_t*)lds;   // 4 regions x 1024 f32x4 (16 KB each)
    if (wave >= 4) {
        #pragma unroll
        for (int im = 0; im < 4; im++)
            #pragma unroll
            for (int jn = 0; jn < 4; jn++)
                red[quadw * 1024 + (im * 4 + jn) * 64 + lane] = acc[im][jn];
    }
    __syncthreads();
    if (wave < 4) {
        #pragma unroll
        for (int jn = 0; jn < 4; jn++) {
            const int gn = bn0 + wcol + jn * 16 + lm;
            const float bias = bmu[gn] + ebias[gn] * bsig[gn];
            #pragma unroll
            for (int im = 0; im < 4; im++) {
                const f32x4_t part = red[quadw * 1024 + (im * 4 + jn) * 64 + lane];
                const int gm0 = bm0 + wrow + im * 16 + quad * 4;
                #pragma unroll
                for (int r = 0; r < 4; r++)
                    C[(size_t)(gm0 + r) * N_OUT + gn] = acc[im][jn][r] + part[r] + bias;
            }
        }
    }
}

// Insurance path if d_ws is too small for the bf16 staging buffers.
__global__ __launch_bounds__(256) void naive_kernel(
    const float* __restrict__ x, const float* __restrict__ wmu,
    const float* __restrict__ wsig, const float* __restrict__ bmu,
    const float* __restrict__ bsig, const float* __restrict__ epsw,
    const float* __restrict__ epsb, float* __restrict__ out)
{
    const int o = blockIdx.x * blockDim.x + threadIdx.x;
    const int b = blockIdx.y;
    const float4* xr = (const float4*)(x + (size_t)b * K_IN);
    const float4* mr = (const float4*)(wmu + (size_t)o * K_IN);
    const float4* sr = (const float4*)(wsig + (size_t)o * K_IN);
    const float4* er = (const float4*)(epsw + (size_t)o * K_IN);
    float s = 0.f;
    for (int k = 0; k < K_IN / 4; k++) {
        float4 xv = xr[k], m = mr[k], sg = sr[k], e = er[k];
        s += xv.x * fmaf(e.x, sg.x, m.x);
        s += xv.y * fmaf(e.y, sg.y, m.y);
        s += xv.z * fmaf(e.z, sg.z, m.z);
        s += xv.w * fmaf(e.w, sg.w, m.w);
    }
    out[(size_t)b * N_OUT + o] = s + bmu[o] + epsb[o] * bsig[o];
}

extern "C" void kernel_launch(void* const* d_in, const int* in_sizes, int n_in,
                              void* d_out, int out_size, void* d_ws, size_t ws_size,
                              hipStream_t stream)
{
    const float* x    = (const float*)d_in[0];
    const float* wmu  = (const float*)d_in[1];
    const float* wsig = (const float*)d_in[2];
    const float* bmu  = (const float*)d_in[3];
    const float* bsig = (const float*)d_in[4];
    const float* epsw = (const float*)d_in[5];
    const float* epsb = (const float*)d_in[6];
    float* out = (float*)d_out;

    const size_t need = ((size_t)N_OUT * K_IN + (size_t)M_BATCH * K_IN) * sizeof(unsigned short);
    if (ws_size >= need) {
        unsigned short* wb = (unsigned short*)d_ws;                  // [N][K] bf16
        unsigned short* xb = wb + (size_t)N_OUT * K_IN;              // [M][K] bf16
        prep_kernel<<<4096, 256, 0, stream>>>(x, wmu, wsig, epsw, wb, xb);
        gemm_bt_kernel<<<256, 512, 0, stream>>>(xb, wb, bmu, bsig, epsb, out);
    } else {
        dim3 grid(N_OUT / 256, M_BATCH);
        naive_kernel<<<grid, 256, 0, stream>>>(x, wmu, wsig, bmu, bsig, epsw, epsb, out);
    }
}

// Round 4
// 246.101 us; speedup vs baseline: 1.0633x; 1.0335x over previous
//
#include <hip/hip_runtime.h>
#include <hip/hip_bf16.h>
#include <stdint.h>

#define M_BATCH 1024
#define N_OUT   4096
#define K_IN    4096

#define BM 128
#define BN 128
#define KPER   (K_IN / 2)        // 2048 per intra-block k-half
#define BK2    32                // k-slab per half per buffer
#define KITER2 (KPER / BK2)      // 64

typedef __attribute__((ext_vector_type(8))) __bf16 bf16x8_t;
typedef __attribute__((ext_vector_type(4))) float f32x4_t;
typedef __attribute__((ext_vector_type(4))) float fvec4;
typedef __attribute__((ext_vector_type(4))) unsigned short us4_t;

__device__ __forceinline__ unsigned short f2bf_bits(float f) {
    union { __hip_bfloat16 h; unsigned short u; } cvt;
    cvt.h = __float2bfloat16(f);  // RNE
    return cvt.u;
}

// Kernel 1: w_bf16 = bf16(mu + eps*sigma); x_bf16 = bf16(x).
// R0 evidence: NT loads on the fp32 streams are REQUIRED (removing them kept
// FETCH_SIZE at 106.5 MB but dropped effective BW 4.9 -> 3.0 TB/s by
// thrashing the 4 MB/XCD L2s). R3 evidence: NT *stores* are WRONG — they
// evicted wb/xb past the MALL, and gemm's FETCH_SIZE showed the full 42 MB
// staging re-fetched from HBM. Plain stores keep wb/xb MALL-resident for the
// consumer. Config: NT loads + plain stores (the measured-best R0 config).
__global__ __launch_bounds__(256) void prep_kernel(
    const float* __restrict__ x,
    const float* __restrict__ wmu,
    const float* __restrict__ wsig,
    const float* __restrict__ epsw,
    unsigned short* __restrict__ wb,
    unsigned short* __restrict__ xb)
{
    const size_t tid = (size_t)blockIdx.x * blockDim.x + threadIdx.x;
    const size_t T   = (size_t)1048576;          // 4096 blocks x 256 threads

    const fvec4* wmu4  = (const fvec4*)wmu;
    const fvec4* wsig4 = (const fvec4*)wsig;
    const fvec4* epsw4 = (const fvec4*)epsw;
    us4_t* wb4 = (us4_t*)wb;

    fvec4 m[4], s[4], e[4];
    #pragma unroll
    for (int r = 0; r < 4; ++r) {
        const size_t i = tid + (size_t)r * T;    // NW4 = 4T exactly
        m[r] = __builtin_nontemporal_load(wmu4  + i);
        s[r] = __builtin_nontemporal_load(wsig4 + i);
        e[r] = __builtin_nontemporal_load(epsw4 + i);
    }
    #pragma unroll
    for (int r = 0; r < 4; ++r) {
        us4_t o;
        o.x = f2bf_bits(fmaf(e[r].x, s[r].x, m[r].x));
        o.y = f2bf_bits(fmaf(e[r].y, s[r].y, m[r].y));
        o.z = f2bf_bits(fmaf(e[r].z, s[r].z, m[r].z));
        o.w = f2bf_bits(fmaf(e[r].w, s[r].w, m[r].w));
        wb4[tid + (size_t)r * T] = o;            // plain store (R0 config)
    }

    // x: NX4 = T exactly, one fvec4 per thread.
    fvec4 v = __builtin_nontemporal_load((const fvec4*)x + tid);
    us4_t o;
    o.x = f2bf_bits(v.x);
    o.y = f2bf_bits(v.y);
    o.z = f2bf_bits(v.z);
    o.w = f2bf_bits(v.w);
    ((us4_t*)xb)[tid] = o;                       // plain store
}

// Kernel 2: C = A @ B^T + bias. 128x128 tile, grid 256 = 1 block/CU,
// XCD-aware bn decode for B-panel L2 locality (unchanged).
// R3 diagnosis: MfmaUtil 23.7% with everything else low = latency stall.
// Per K-iter compute (~155 cy of MFMA) couldn't cover the ~600-900 cy
// global->LDS latency, and __syncthreads' implicit s_waitcnt vmcnt(0)
// drained the prefetch queue every iteration; 1 block/CU means no
// inter-block overlap to mask it (m97's crutch).
// R3 fix (T3+T4): 4 x 32 KB LDS buffers (BK=32 per k-half per buffer,
// 64 iters), prefetch issued THREE slabs ahead, raw s_barrier + counted
// s_waitcnt vmcnt(8) — never 0 in the main loop, so 8-12 loads stay in
// flight across every barrier. vmcnt peels 8->8->4->0 over the last iters.
// LDS chunk swizzle for the 4-chunk layout: phys_ch = quad ^ ((lm>>1)&3)
// (2-way bank aliasing within each 16-lane phase = free per m136), applied
// to the GLOBAL source address so global_load_lds stays linear (m104/m173).
__global__ __launch_bounds__(512, 2) void gemm_bt_kernel(
    const unsigned short* __restrict__ A,
    const unsigned short* __restrict__ B,
    const float* __restrict__ bmu,
    const float* __restrict__ bsig,
    const float* __restrict__ ebias,
    float* __restrict__ C)
{
    // 4 buffers x 16384 elems (32 KB). Per buffer (elems):
    //   A: [half:2][row:128][ch:4]*8 at 0      (8192 elems)
    //   B: same shape at 8192.
    __shared__ unsigned short lds[4 * 16384];

    const int t   = threadIdx.x;
    const int b   = blockIdx.x;
    const int bn  = (b & 7) | (((b >> 3) & 3) << 3);   // 0..31, same-bn => same XCD
    const int bm  = b >> 5;                             // 0..7
    const int bm0 = bm * BM;
    const int bn0 = bn * BN;
    const int lane  = t & 63;
    const int wave  = t >> 6;
    const int khalf = wave >> 2;          // 0/1: which k-half this wave computes
    const int quadw = wave & 3;
    const int wrow  = (quadw >> 1) * 64;
    const int wcol  = (quadw & 1) * 64;
    const int lm    = lane & 15;
    const int quad  = lane >> 4;
    const int fq    = quad ^ ((lm >> 1) & 3);   // de-swizzled phys chunk (im-invariant)

    f32x4_t acc[4][4] = {};

    // Staging: thread t stages 4 chunks/iter: s=0,1 -> A half0/1; s=2,3 -> B.
    // Phys slot (row = t>>2, ch = t&3) holds logical chunk (t&3)^((t>>3)&3)
    // (note t>>3 == row>>1), pre-swizzled at the global source.
    const int row   = t >> 2;                     // 0..127
    const int chlog = (t & 3) ^ ((t >> 3) & 3);
    const unsigned short* srcs[4];
    srcs[0] = A + (size_t)(bm0 + row) * K_IN + chlog * 8;
    srcs[1] = srcs[0] + KPER;
    srcs[2] = B + (size_t)(bn0 + row) * K_IN + chlog * 8;
    srcs[3] = srcs[2] + KPER;
    char* dstt = (char*)lds + t * 16;

    auto STAGE = [&](int it) {
        const int koff = it * BK2;                // elems
        char* d = dstt + (it & 3) * 32768;
        #pragma unroll
        for (int s = 0; s < 4; ++s)
            __builtin_amdgcn_global_load_lds(
                (const __attribute__((address_space(1))) void*)(srcs[s] + koff),
                (__attribute__((address_space(3))) void*)(d + s * 8192), 16, 0, 0);
    };

    auto COMPUTE = [&](int it) {
        const unsigned short* Lb = lds + (it & 3) * 16384;
        const unsigned short* Ah = Lb + khalf * 4096 + (wrow + lm) * 32 + fq * 8;
        const unsigned short* Bh = Lb + 8192 + khalf * 4096 + (wcol + lm) * 32 + fq * 8;
        bf16x8_t a_frag[4], b_frag[4];
        #pragma unroll
        for (int im = 0; im < 4; im++)
            a_frag[im] = *(const bf16x8_t*)(Ah + im * 512);
        #pragma unroll
        for (int jn = 0; jn < 4; jn++)
            b_frag[jn] = *(const bf16x8_t*)(Bh + jn * 512);
        #pragma unroll
        for (int im = 0; im < 4; im++)
            #pragma unroll
            for (int jn = 0; jn < 4; jn++)
                acc[im][jn] = __builtin_amdgcn_mfma_f32_16x16x32_bf16(
                    a_frag[im], b_frag[jn], acc[im][jn], 0, 0, 0);
        // Pin this iter's ds_reads/lgkm-waits/MFMAs before the next barrier:
        // prevents sinking past the point where buf((it+4)&3)==buf(it&3)
        // gets overwritten by a later STAGE.
        __builtin_amdgcn_sched_barrier(0);
    };

    // Prologue: 3 slabs in flight (12 load instrs per wave).
    STAGE(0); STAGE(1); STAGE(2);

    // Main loop: counted vmcnt — 8 newest loads (2 future slabs) stay in
    // flight across the barrier; the slab about to be consumed is complete.
    for (int it = 0; it < KITER2 - 3; ++it) {      // 0..60, issues up to slab 63
        asm volatile("s_waitcnt vmcnt(8)\n\ts_barrier" ::: "memory");
        STAGE(it + 3);
        COMPUTE(it);
    }
    asm volatile("s_waitcnt vmcnt(8)\n\ts_barrier" ::: "memory");
    COMPUTE(KITER2 - 3);
    asm volatile("s_waitcnt vmcnt(4)\n\ts_barrier" ::: "memory");
    COMPUTE(KITER2 - 2);
    asm volatile("s_waitcnt vmcnt(0)\n\ts_barrier" ::: "memory");
    COMPUTE(KITER2 - 1);

    // Epilogue: reduce the two k-halves through LDS, add bias, store once.
    // Last compute read buffer 3 (bytes [96K,128K)); the 64 KB reduction
    // region uses buffers 0-1 (bytes [0,64K)) — disjoint, no barrier needed
    // before the writes (all waves passed the final s_barrier already).
    f32x4_t* red = (f32x4_t*)lds;   // 4 regions x 1024 f32x4 (16 KB each)
    if (wave >= 4) {
        #pragma unroll
        for (int im = 0; im < 4; im++)
            #pragma unroll
            for (int jn = 0; jn < 4; jn++)
                red[quadw * 1024 + (im * 4 + jn) * 64 + lane] = acc[im][jn];
    }
    __syncthreads();
    if (wave < 4) {
        #pragma unroll
        for (int jn = 0; jn < 4; jn++) {
            const int gn = bn0 + wcol + jn * 16 + lm;
            const float bias = bmu[gn] + ebias[gn] * bsig[gn];
            #pragma unroll
            for (int im = 0; im < 4; im++) {
                const f32x4_t part = red[quadw * 1024 + (im * 4 + jn) * 64 + lane];
                const int gm0 = bm0 + wrow + im * 16 + quad * 4;
                #pragma unroll
                for (int r = 0; r < 4; r++)
                    C[(size_t)(gm0 + r) * N_OUT + gn] = acc[im][jn][r] + part[r] + bias;
            }
        }
    }
}

// Insurance path if d_ws is too small for the bf16 staging buffers.
__global__ __launch_bounds__(256) void naive_kernel(
    const float* __restrict__ x, const float* __restrict__ wmu,
    const float* __restrict__ wsig, const float* __restrict__ bmu,
    const float* __restrict__ bsig, const float* __restrict__ epsw,
    const float* __restrict__ epsb, float* __restrict__ out)
{
    const int o = blockIdx.x * blockDim.x + threadIdx.x;
    const int b = blockIdx.y;
    const float4* xr = (const float4*)(x + (size_t)b * K_IN);
    const float4* mr = (const float4*)(wmu + (size_t)o * K_IN);
    const float4* sr = (const float4*)(wsig + (size_t)o * K_IN);
    const float4* er = (const float4*)(epsw + (size_t)o * K_IN);
    float s = 0.f;
    for (int k = 0; k < K_IN / 4; k++) {
        float4 xv = xr[k], m = mr[k], sg = sr[k], e = er[k];
        s += xv.x * fmaf(e.x, sg.x, m.x);
        s += xv.y * fmaf(e.y, sg.y, m.y);
        s += xv.z * fmaf(e.z, sg.z, m.z);
        s += xv.w * fmaf(e.w, sg.w, m.w);
    }
    out[(size_t)b * N_OUT + o] = s + bmu[o] + epsb[o] * bsig[o];
}

extern "C" void kernel_launch(void* const* d_in, const int* in_sizes, int n_in,
                              void* d_out, int out_size, void* d_ws, size_t ws_size,
                              hipStream_t stream)
{
    const float* x    = (const float*)d_in[0];
    const float* wmu  = (const float*)d_in[1];
    const float* wsig = (const float*)d_in[2];
    const float* bmu  = (const float*)d_in[3];
    const float* bsig = (const float*)d_in[4];
    const float* epsw = (const float*)d_in[5];
    const float* epsb = (const float*)d_in[6];
    float* out = (float*)d_out;

    const size_t need = ((size_t)N_OUT * K_IN + (size_t)M_BATCH * K_IN) * sizeof(unsigned short);
    if (ws_size >= need) {
        unsigned short* wb = (unsigned short*)d_ws;                  // [N][K] bf16
        unsigned short* xb = wb + (size_t)N_OUT * K_IN;              // [M][K] bf16
        prep_kernel<<<4096, 256, 0, stream>>>(x, wmu, wsig, epsw, wb, xb);
        gemm_bt_kernel<<<256, 512, 0, stream>>>(xb, wb, bmu, bsig, epsb, out);
    } else {
        dim3 grid(N_OUT / 256, M_BATCH);
        naive_kernel<<<grid, 256, 0, stream>>>(x, wmu, wsig, bmu, bsig, epsw, epsb, out);
    }
}